// Round 5
// baseline (2429.763 us; speedup 1.0000x reference)
//
#include <hip/hip_runtime.h>

#define NN 2048
#define MM 2048
#define KC 8
#define DD 64
#define PN (NN + 4*KC + 32)            // padded potential-array length (x side)
#define PM (MM + 4*KC + 32)
#define TOTROWS (2*(NN+MM))
#define CPAD (2*NN*MM + NN*NN + MM*MM + 6*(NN+MM) + 256)
#define PADV 3.0e38f
#define LN2F    0.6931471805599453f
#define INVLN2F 1.4426950408889634f

struct Params {
  const float* x; const float* centers; const float* ftarg;
  const float* y; const int* predy;
  float* out;
  int* pred_x;
  int* zr;   // [0,KC)=cnt_x [KC,2KC)=cnt_y [2KC,3KC)=fill_x [3KC,4KC)=fill_y [4KC,4KC+64)=barriers
  int* off_x; int* off_y; int* pox; int* poy;
  int* boxy; int* byx; int* boxx; int* boyy;   // KC+1 each, absolute ascending bases in Call
  int* pc_x; int* pc_y;
  float* Xp; float* Yp; float* xn; float* yn;
  float* Fab; float* Faa; float* Gab; float* Gbb;  // 2*PN / 2*PM ping-pong
  float* la; float* lb; int* valid; float* acc;
  int4* meta; float* fin; int* dsti;               // legacy-path row tables
  float* Call;
};

__device__ __forceinline__ float wredmax(float v){
  #pragma unroll
  for(int m=32;m>=1;m>>=1) v = fmaxf(v, __shfl_xor(v,m,64));
  return v;
}
__device__ __forceinline__ float wredsum(float v){
  #pragma unroll
  for(int m=32;m>=1;m>>=1) v += __shfl_xor(v,m,64);
  return v;
}

// single-pass online wave LSE over a padded row (pads hold 3e38 -> contribute 0)
// w(c) = s1*(pot[c]-C[c]) + hb2  in log2 domain;  returns -eps*ln(sum exp)
__device__ __forceinline__ float softmin_row(const float* __restrict__ Cb,
                                             const float* __restrict__ pot,
                                             float s1, float hb2, int rs,
                                             int lane, float eps){
  float m = -3.4e38f, s = 0.f;
  for(int c0 = lane*4; c0 < rs; c0 += 256){
    float4 cv = *(const float4*)(Cb + c0);
    float4 pv = *(const float4*)(pot + c0);
    float w0 = fmaf(pv.x - cv.x, s1, hb2);
    float w1 = fmaf(pv.y - cv.y, s1, hb2);
    float w2 = fmaf(pv.z - cv.z, s1, hb2);
    float w3 = fmaf(pv.w - cv.w, s1, hb2);
    float lm = fmaxf(fmaxf(w0,w1), fmaxf(w2,w3));
    float mn = fmaxf(m, lm);
    s = s*exp2f(m-mn) + (exp2f(w0-mn)+exp2f(w1-mn)) + (exp2f(w2-mn)+exp2f(w3-mn));
    m = mn;
  }
  float M = wredmax(m);
  s = s * exp2f(m - M);
  float S = wredsum(s);
  return -eps*LN2F*(M + log2f(S));
}

// sense-counting barrier over `members` blocks; g = expected generation (monotone)
__device__ __forceinline__ void xbar(int* cnt, int* gen, int members, int g){
  __syncthreads();
  if(threadIdx.x==0){
    __threadfence();
    int prev = __hip_atomic_fetch_add(cnt, 1, __ATOMIC_ACQ_REL, __HIP_MEMORY_SCOPE_AGENT);
    if(prev == members-1){
      __hip_atomic_store(cnt, 0, __ATOMIC_RELAXED, __HIP_MEMORY_SCOPE_AGENT);
      __hip_atomic_store(gen, g, __ATOMIC_RELEASE, __HIP_MEMORY_SCOPE_AGENT);
    } else {
      int gv;
      do { __builtin_amdgcn_s_sleep(2);
           gv = __hip_atomic_load(gen, __ATOMIC_ACQUIRE, __HIP_MEMORY_SCOPE_AGENT);
      } while(gv < g);
    }
  }
  __syncthreads();
  __threadfence();
}

__device__ __forceinline__ float dot64(const float4* __restrict__ a,
                                       const float4* __restrict__ b){
  float d=0.f;
  #pragma unroll
  for(int q=0;q<DD/4;q++){ float4 av=a[q], bv=b[q];
    d += av.x*bv.x + av.y*bv.y + av.z*bv.z + av.w*bv.w; }
  return d;
}

// ---------- k0: zero potentials (legacy fallback path only) ----------
__global__ void __launch_bounds__(256) k0_init(Params p){
  int g = blockIdx.x*blockDim.x + threadIdx.x, n = gridDim.x*blockDim.x;
  for(int i=g;i<2*PN;i+=n){ p.Fab[i]=0.f; p.Faa[i]=0.f; }
  for(int j=g;j<2*PM;j+=n){ p.Gab[j]=0.f; p.Gbb[j]=0.f; }
}

// ---------- k1: kmeans predict + counts ----------
__global__ void __launch_bounds__(256) k1_predict(Params p){
  int gtid = blockIdx.x*blockDim.x + threadIdx.x, nth = gridDim.x*blockDim.x;
  for(int i=gtid;i<NN;i+=nth){
    const float4* xi = (const float4*)(p.x + i*DD);
    float best = 3.4e38f; int bk = 0;
    for(int k=0;k<KC;k++){
      const float4* ck = (const float4*)(p.centers + k*DD);
      float s = 0.f;
      #pragma unroll
      for(int q=0;q<DD/4;q++){ float4 a=xi[q], b=ck[q];
        float dx=a.x-b.x, dy=a.y-b.y, dz=a.z-b.z, dw=a.w-b.w;
        s += dx*dx+dy*dy+dz*dz+dw*dw; }
      if(s < best){ best = s; bk = k; }
    }
    p.pred_x[i] = bk;
    atomicAdd(&p.zr[bk], 1);
  }
  for(int j=gtid;j<MM;j+=nth) atomicAdd(&p.zr[KC + p.predy[j]], 1);
}

// ---------- k2: serial offsets / padded bases / log-weights / filling loss ----------
__global__ void k2_serial(Params p){
  if(threadIdx.x!=0 || blockIdx.x!=0) return;
  int ox=0, oy=0, px=0, py=0;
  float lf = 0.f;
  for(int k=0;k<KC;k++){
    int nk=p.zr[k], mk=p.zr[KC+k];
    p.off_x[k]=ox; p.off_y[k]=oy; p.pox[k]=px; p.poy[k]=py;
    ox+=nk; oy+=mk;
    px=(px+nk+3)&~3; py=(py+mk+3)&~3;
    p.la[k] = -logf(fmaxf((float)nk,1.f));
    p.lb[k] = -logf(fmaxf((float)mk,1.f));
    p.valid[k] = (nk>0 && mk>0) ? 1 : 0;
    float df = (float)nk/(float)NN - p.ftarg[k];
    lf += df*df;
  }
  p.off_x[KC]=ox; p.off_y[KC]=oy;
  int run=0;
  for(int k=0;k<KC;k++){ int nk=p.zr[k], mk=p.zr[KC+k];
    p.boxy[k]=run; run += nk*((mk+3)&~3); } p.boxy[KC]=run;
  for(int k=0;k<KC;k++){ int nk=p.zr[k], mk=p.zr[KC+k];
    p.byx[k]=run;  run += mk*((nk+3)&~3); } p.byx[KC]=run;
  for(int k=0;k<KC;k++){ int nk=p.zr[k];
    p.boxx[k]=run; run += nk*((nk+3)&~3); } p.boxx[KC]=run;
  for(int k=0;k<KC;k++){ int mk=p.zr[KC+k];
    p.boyy[k]=run; run += mk*((mk+3)&~3); } p.boyy[KC]=run;
  *p.acc = lf/(float)KC;
}

// ---------- k3: pack points by cluster ----------
__global__ void __launch_bounds__(256) k3_pack(Params p){
  int gtid = blockIdx.x*blockDim.x + threadIdx.x, nth = gridDim.x*blockDim.x;
  for(int i=gtid;i<NN;i+=nth){
    int k = p.pred_x[i];
    int pos = p.off_x[k] + atomicAdd(&p.zr[2*KC+k],1);
    p.pc_x[pos] = k;
    const float4* xi = (const float4*)(p.x + i*DD);
    float4* dst = (float4*)(p.Xp + (size_t)pos*DD);
    float s=0.f;
    #pragma unroll
    for(int q=0;q<DD/4;q++){ float4 v=xi[q]; dst[q]=v;
      s += v.x*v.x+v.y*v.y+v.z*v.z+v.w*v.w; }
    p.xn[pos]=s;
  }
  for(int j=gtid;j<MM;j+=nth){
    int k = p.predy[j];
    int pos = p.off_y[k] + atomicAdd(&p.zr[3*KC+k],1);
    p.pc_y[pos] = k;
    const float4* yj = (const float4*)(p.y + j*DD);
    float4* dst = (float4*)(p.Yp + (size_t)pos*DD);
    float s=0.f;
    #pragma unroll
    for(int q=0;q<DD/4;q++){ float4 v=yj[q]; dst[q]=v;
      s += v.x*v.x+v.y*v.y+v.z*v.z+v.w*v.w; }
    p.yn[pos]=s;
  }
}

// ---------- k4: padded cost blocks (all writes coalesced) + legacy row tables ----------
__global__ void __launch_bounds__(256) k4_cost(Params p){
  int gtid = blockIdx.x*blockDim.x + threadIdx.x, nth = gridDim.x*blockDim.x;
  int bxyA[KC+1], byxA[KC+1], bxxA[KC+1], byyA[KC+1];
  int cx[KC], cy[KC], ox[KC], oy[KC];
  #pragma unroll
  for(int k=0;k<KC;k++){ bxyA[k]=p.boxy[k]; byxA[k]=p.byx[k]; bxxA[k]=p.boxx[k]; byyA[k]=p.boyy[k];
    cx[k]=p.zr[k]; cy[k]=p.zr[KC+k]; ox[k]=p.off_x[k]; oy[k]=p.off_y[k]; }
  bxyA[KC]=p.boxy[KC]; byxA[KC]=p.byx[KC]; bxxA[KC]=p.boxx[KC]; byyA[KC]=p.boyy[KC];

  // XY
  for(int idx=gtid; idx<bxyA[KC]; idx+=nth){
    int k=0;
    #pragma unroll
    for(int q=1;q<KC;q++) if(idx>=bxyA[q]) k=q;
    int mk=cy[k], rs=(mk+3)&~3;
    int lo=idx-bxyA[k], r=lo/rs, c=lo-r*rs;
    float v=PADV;
    if(c<mk){
      float dot = dot64((const float4*)(p.Xp+(size_t)(ox[k]+r)*DD),
                        (const float4*)(p.Yp+(size_t)(oy[k]+c)*DD));
      v = 0.5f*fmaxf(p.xn[ox[k]+r]+p.yn[oy[k]+c]-2.f*dot, 0.f);
    }
    p.Call[idx]=v;
  }
  // YX (direct compute, coalesced)
  for(int idx=byxA[0]+gtid; idx<byxA[KC]; idx+=nth){
    int k=0;
    #pragma unroll
    for(int q=1;q<KC;q++) if(idx>=byxA[q]) k=q;
    int nk=cx[k], rs=(nk+3)&~3;
    int lo=idx-byxA[k], r=lo/rs, c=lo-r*rs;
    float v=PADV;
    if(c<nk){
      float dot = dot64((const float4*)(p.Yp+(size_t)(oy[k]+r)*DD),
                        (const float4*)(p.Xp+(size_t)(ox[k]+c)*DD));
      v = 0.5f*fmaxf(p.yn[oy[k]+r]+p.xn[ox[k]+c]-2.f*dot, 0.f);
    }
    p.Call[idx]=v;
  }
  // XX
  for(int idx=bxxA[0]+gtid; idx<bxxA[KC]; idx+=nth){
    int k=0;
    #pragma unroll
    for(int q=1;q<KC;q++) if(idx>=bxxA[q]) k=q;
    int nk=cx[k], rs=(nk+3)&~3;
    int lo=idx-bxxA[k], r=lo/rs, c=lo-r*rs;
    float v=PADV;
    if(c<nk){
      float dot = dot64((const float4*)(p.Xp+(size_t)(ox[k]+r)*DD),
                        (const float4*)(p.Xp+(size_t)(ox[k]+c)*DD));
      v = 0.5f*fmaxf(p.xn[ox[k]+r]+p.xn[ox[k]+c]-2.f*dot, 0.f);
    }
    p.Call[idx]=v;
  }
  // YY
  for(int idx=byyA[0]+gtid; idx<byyA[KC]; idx+=nth){
    int k=0;
    #pragma unroll
    for(int q=1;q<KC;q++) if(idx>=byyA[q]) k=q;
    int mk=cy[k], rs=(mk+3)&~3;
    int lo=idx-byyA[k], r=lo/rs, c=lo-r*rs;
    float v=PADV;
    if(c<mk){
      float dot = dot64((const float4*)(p.Yp+(size_t)(oy[k]+r)*DD),
                        (const float4*)(p.Yp+(size_t)(oy[k]+c)*DD));
      v = 0.5f*fmaxf(p.yn[oy[k]+r]+p.yn[oy[k]+c]-2.f*dot, 0.f);
    }
    p.Call[idx]=v;
  }

  // legacy row tables (used only by the fallback path)
  for(int row=gtid; row<TOTROWS; row+=nth){
    int grp = (row>=NN) + (row>=NN+MM) + (row>=2*NN+MM);
    int pidx = row - ((grp==0)?0:(grp==1)?NN:(grp==2)?(NN+MM):(2*NN+MM));
    int k, coff, hoff, rs, di; float hc, fv;
    if(grp==0){ k=p.pc_x[pidx]; int r=pidx-ox[k]; rs=(cy[k]+3)&~3;
      coff=bxyA[k]+r*rs; hoff=p.poy[k]; hc=p.lb[k]; di=p.pox[k]+r;
      fv = p.valid[k] ?  1.f/(float)cx[k] : 0.f; }
    else if(grp==1){ k=p.pc_y[pidx]; int r=pidx-oy[k]; rs=(cx[k]+3)&~3;
      coff=byxA[k]+r*rs; hoff=p.pox[k]; hc=p.la[k]; di=p.poy[k]+r;
      fv = p.valid[k] ?  1.f/(float)cy[k] : 0.f; }
    else if(grp==2){ k=p.pc_x[pidx]; int r=pidx-ox[k]; rs=(cx[k]+3)&~3;
      coff=bxxA[k]+r*rs; hoff=p.pox[k]; hc=p.la[k]; di=p.pox[k]+r;
      fv = p.valid[k] ? -1.f/(float)cx[k] : 0.f; }
    else { k=p.pc_y[pidx]; int r=pidx-oy[k]; rs=(cy[k]+3)&~3;
      coff=byyA[k]+r*rs; hoff=p.poy[k]; hc=p.lb[k]; di=p.poy[k]+r;
      fv = p.valid[k] ? -1.f/(float)cy[k] : 0.f; }
    p.meta[row] = make_int4(coff, hoff, rs, __float_as_int(hc));
    p.fin[row]  = fv;
    p.dsti[row] = di;
  }
}

// ---------- MAIN PATH: one persistent kernel, per-cluster barriers ----------
__global__ void __launch_bounds__(256,2) k_chain(Params p){
  const int tid=threadIdx.x, lane=tid&63, wv=tid>>6;
  const int BPC = gridDim.x/KC;
  const int k   = blockIdx.x % KC;       // XCD-locality heuristic
  const int sub = blockIdx.x / KC;
  const int WPC = BPC*4;
  const int mywave = sub*4 + wv;
  int* bar = p.zr + 4*KC;
  int* cnt = bar + 2*k; int* gen = bar + 2*k + 1;

  const int nk=p.zr[k], mk=p.zr[KC+k];
  const int pox=p.pox[k], poy=p.poy[k];
  const int bxy=p.boxy[k], byx=p.byx[k], bxx=p.boxx[k], byy=p.boyy[k];
  const int rsy=(mk+3)&~3, rsx=(nk+3)&~3;
  const float la=p.la[k], lb=p.lb[k];
  const int valid=p.valid[k];
  const int nr = 2*(nk+mk);

  // zero cluster's potentials (buffer 0)
  for(int i=sub*256+tid;i<nk;i+=BPC*256){ p.Fab[pox+i]=0.f; p.Faa[pox+i]=0.f; }
  for(int j=sub*256+tid;j<mk;j+=BPC*256){ p.Gab[poy+j]=0.f; p.Gbb[poy+j]=0.f; }
  xbar(cnt,gen,BPC,1);

  const double EMIN = 0.05*0.05, S2 = 0.8*0.8;
  int neps=0; { double e=16.0; while(e>EMIN){neps++; e*=S2;} neps++; }   // 21
  double e_run=16.0;
  for(int it=0; it<neps; ++it){
    float eps = (it==neps-1)?(float)EMIN:(float)e_run;
    e_run*=S2;
    float s1 = (1.0f/eps)*INVLN2F;
    int cur=it&1, nxt=1-cur;
    const float* Fo=p.Fab+cur*PN; const float* Go=p.Gab+cur*PM;
    const float* Ao=p.Faa+cur*PN; const float* Bo=p.Gbb+cur*PM;
    float* Fn=p.Fab+nxt*PN; float* Gn=p.Gab+nxt*PM;
    float* An=p.Faa+nxt*PN; float* Bn=p.Gbb+nxt*PM;
    for(int t=mywave; t<nr; t+=WPC){
      const float* Cb; const float* pot; float hb2; int rs; float* dst; float old; int di;
      if(t<nk){ int r=t;
        Cb=p.Call+bxy+(size_t)r*rsy; pot=Go+poy; hb2=lb*INVLN2F; rs=rsy;
        dst=Fn; old=Fo[pox+r]; di=pox+r; }
      else if(t<nk+mk){ int r=t-nk;
        Cb=p.Call+byx+(size_t)r*rsx; pot=Fo+pox; hb2=la*INVLN2F; rs=rsx;
        dst=Gn; old=Go[poy+r]; di=poy+r; }
      else if(t<2*nk+mk){ int r=t-nk-mk;
        Cb=p.Call+bxx+(size_t)r*rsx; pot=Ao+pox; hb2=la*INVLN2F; rs=rsx;
        dst=An; old=Ao[pox+r]; di=pox+r; }
      else { int r=t-2*nk-mk;
        Cb=p.Call+byy+(size_t)r*rsy; pot=Bo+poy; hb2=lb*INVLN2F; rs=rsy;
        dst=Bn; old=Bo[poy+r]; di=poy+r; }
      float L = softmin_row(Cb, pot, s1, hb2, rs, lane, eps);
      if(lane==0) dst[di] = 0.5f*(old+L);
    }
    xbar(cnt,gen,BPC,2+it);
  }

  // epilogue: final extrapolation at eps_min + per-block reduction into acc
  {
    int cur = neps&1;
    float eps=(float)EMIN; float s1=(1.0f/eps)*INVLN2F;
    const float* Fo=p.Fab+cur*PN; const float* Go=p.Gab+cur*PM;
    const float* Ao=p.Faa+cur*PN; const float* Bo=p.Gbb+cur*PM;
    float part=0.f;
    if(valid){
      for(int t=mywave; t<nr; t+=WPC){
        const float* Cb; const float* pot; float hb2; int rs; float fv;
        if(t<nk){ int r=t;
          Cb=p.Call+bxy+(size_t)r*rsy; pot=Go+poy; hb2=lb*INVLN2F; rs=rsy; fv= 1.f/(float)nk; }
        else if(t<nk+mk){ int r=t-nk;
          Cb=p.Call+byx+(size_t)r*rsx; pot=Fo+pox; hb2=la*INVLN2F; rs=rsx; fv= 1.f/(float)mk; }
        else if(t<2*nk+mk){ int r=t-nk-mk;
          Cb=p.Call+bxx+(size_t)r*rsx; pot=Ao+pox; hb2=la*INVLN2F; rs=rsx; fv=-1.f/(float)nk; }
        else { int r=t-2*nk-mk;
          Cb=p.Call+byy+(size_t)r*rsy; pot=Bo+poy; hb2=lb*INVLN2F; rs=rsy; fv=-1.f/(float)mk; }
        float L = softmin_row(Cb, pot, s1, hb2, rs, lane, eps);
        if(lane==0) part += L*fv;
      }
    }
    __shared__ float sp[4];
    if(lane==0) sp[wv]=part;
    __syncthreads();
    if(tid==0){
      float v = sp[0]+sp[1]+sp[2]+sp[3];
      if(v!=0.f) atomicAdd(p.acc, v);
    }
  }
  xbar(bar+32, bar+33, gridDim.x, 1);       // one global barrier
  if(blockIdx.x==0 && tid==0)
    p.out[0] = __hip_atomic_load(p.acc, __ATOMIC_RELAXED, __HIP_MEMORY_SCOPE_AGENT);
}

// ---------- legacy fallback: per-eps kernels ----------
__global__ void __launch_bounds__(256) k_iter(Params p, float eps, int cur){
  int row  = blockIdx.x*4 + (threadIdx.x>>6);
  int lane = threadIdx.x & 63;
  if(row>=TOTROWS) return;
  int4 mt = p.meta[row];
  int grp = (row>=NN) + (row>=NN+MM) + (row>=2*NN+MM);
  const float* po = (grp==0)?(p.Gab+cur*PM):(grp==1)?(p.Fab+cur*PN)
                   :(grp==2)?(p.Faa+cur*PN):(p.Gbb+cur*PM);
  float* fam = (grp==0)?p.Fab:(grp==1)?p.Gab:(grp==2)?p.Faa:p.Gbb;
  int famN = (grp==0||grp==2)?PN:PM;
  float s1=(1.0f/eps)*INVLN2F, hb2=__int_as_float(mt.w)*INVLN2F;
  float L = softmin_row(p.Call+mt.x, po+mt.y, s1, hb2, mt.z, lane, eps);
  int di = p.dsti[row];
  if(lane==0) fam[(1-cur)*famN+di] = 0.5f*(fam[cur*famN+di]+L);
}

__global__ void __launch_bounds__(256) k_final(Params p, float eps, int cur){
  __shared__ float bacc;
  if(threadIdx.x==0) bacc=0.f;
  __syncthreads();
  int row  = blockIdx.x*4 + (threadIdx.x>>6);
  int lane = threadIdx.x & 63;
  if(row<TOTROWS){
    float fv = p.fin[row];
    if(fv != 0.f){
      int4 mt = p.meta[row];
      int grp = (row>=NN) + (row>=NN+MM) + (row>=2*NN+MM);
      const float* po = (grp==0)?(p.Gab+cur*PM):(grp==1)?(p.Fab+cur*PN)
                       :(grp==2)?(p.Faa+cur*PN):(p.Gbb+cur*PM);
      float s1=(1.0f/eps)*INVLN2F, hb2=__int_as_float(mt.w)*INVLN2F;
      float L = softmin_row(p.Call+mt.x, po+mt.y, s1, hb2, mt.z, lane, eps);
      if(lane==0) atomicAdd(&bacc, L*fv);
    }
  }
  __syncthreads();
  if(threadIdx.x==0 && bacc != 0.f) atomicAdd(p.acc, bacc);
}

__global__ void k_out(Params p){
  if(threadIdx.x==0 && blockIdx.x==0) p.out[0] = *p.acc;
}

extern "C" void kernel_launch(void* const* d_in, const int* in_sizes, int n_in,
                              void* d_out, int out_size, void* d_ws, size_t ws_size,
                              hipStream_t stream)
{
  Params p;
  p.x       = (const float*)d_in[0];
  p.centers = (const float*)d_in[1];
  p.ftarg   = (const float*)d_in[2];
  p.y       = (const float*)d_in[3];
  p.predy   = (const int*)d_in[4];
  p.out     = (float*)d_out;

  char* w = (char*)d_ws; size_t o = 0;
  auto A = [&](size_t bytes)->char*{ char* r = w + o; o = (o + bytes + 255) & ~(size_t)255; return r; };
  p.pred_x=(int*)A(NN*4);
  p.zr    =(int*)A((4*KC+64)*4);
  p.off_x=(int*)A((KC+1)*4); p.off_y=(int*)A((KC+1)*4);
  p.pox=(int*)A(KC*4); p.poy=(int*)A(KC*4);
  p.boxy=(int*)A((KC+1)*4); p.byx=(int*)A((KC+1)*4);
  p.boxx=(int*)A((KC+1)*4); p.boyy=(int*)A((KC+1)*4);
  p.pc_x=(int*)A(NN*4); p.pc_y=(int*)A(MM*4);
  p.Xp=(float*)A((size_t)NN*DD*4); p.Yp=(float*)A((size_t)MM*DD*4);
  p.xn=(float*)A(NN*4); p.yn=(float*)A(MM*4);
  p.Fab=(float*)A((size_t)2*PN*4); p.Faa=(float*)A((size_t)2*PN*4);
  p.Gab=(float*)A((size_t)2*PM*4); p.Gbb=(float*)A((size_t)2*PM*4);
  p.la=(float*)A(KC*4); p.lb=(float*)A(KC*4); p.valid=(int*)A(KC*4);
  p.acc=(float*)A(4);
  p.meta=(int4*)A((size_t)TOTROWS*16); p.fin=(float*)A((size_t)TOTROWS*4);
  p.dsti=(int*)A((size_t)TOTROWS*4);
  p.Call=(float*)A((size_t)CPAD*4);

  // zero counters + barrier state (ws is poisoned before every call)
  hipMemsetAsync(p.zr, 0, (4*KC+64)*4, stream);

  hipLaunchKernelGGL(k1_predict, dim3(16),   dim3(256), 0, stream, p);
  hipLaunchKernelGGL(k2_serial,  dim3(1),    dim3(64),  0, stream, p);
  hipLaunchKernelGGL(k3_pack,    dim3(16),   dim3(256), 0, stream, p);
  hipLaunchKernelGGL(k4_cost,    dim3(2048), dim3(256), 0, stream, p);

  // cooperative grid sized from the runtime's occupancy answer (round-2 lesson)
  int numCU = 0;
  if(hipDeviceGetAttribute(&numCU, hipDeviceAttributeMultiprocessorCount, 0)
     != hipSuccess || numCU <= 0) numCU = 256;
  int bpc = 0;
  hipError_t qerr = hipOccupancyMaxActiveBlocksPerMultiprocessor(&bpc, k_chain, 256, 0);
  int G = (qerr==hipSuccess && bpc>0) ? bpc*numCU : 0;
  if(G > 512) G = 512;
  G &= ~7;                                   // multiple of KC

  bool done = false;
  if(G >= 8){
    void* args[] = { &p };
    if(hipLaunchCooperativeKernel((void*)k_chain, dim3(G), dim3(256), args, 0, stream)
       == hipSuccess) done = true;
    else (void)hipGetLastError();
  }
  if(!done){
    // legacy proven path: 21 per-eps kernels
    hipLaunchKernelGGL(k0_init, dim3(32), dim3(256), 0, stream, p);
    const double EMIN = 0.05*0.05, S2 = 0.8*0.8;
    float epsv[40]; int ne = 0;
    { double e = 16.0; while(e > EMIN){ epsv[ne++] = (float)e; e *= S2; } epsv[ne++] = (float)EMIN; }
    for(int it=0; it<ne; ++it)
      hipLaunchKernelGGL(k_iter, dim3(TOTROWS/4), dim3(256), 0, stream, p, epsv[it], it&1);
    hipLaunchKernelGGL(k_final, dim3(TOTROWS/4), dim3(256), 0, stream, p, (float)EMIN, ne&1);
    hipLaunchKernelGGL(k_out, dim3(1), dim3(64), 0, stream, p);
  }
}

// Round 6
// 368.718 us; speedup vs baseline: 6.5898x; 6.5898x over previous
//
#include <hip/hip_runtime.h>

#define NN 2048
#define MM 2048
#define KC 8
#define DD 64
#define PN (NN + 4*KC + 32)
#define PM (MM + 4*KC + 32)
#define TOTROWS (2*(NN+MM))
#define CPAD (2*NN*MM + NN*NN + MM*MM + 6*(NN+MM) + 256)
#define PADV 3.0e38f
#define LN2F    0.6931471805599453f
#define INVLN2F 1.4426950408889634f

struct Params {
  const float* x; const float* centers; const float* ftarg;
  const float* y; const int* predy;
  float* out;
  int* zr;                                   // [0] = done counter for k_final
  int* cntx; int* cnty; int* off_x; int* off_y; int* pox; int* poy;
  int* bxy; int* byx; int* bxx; int* byy;    // per-cluster segment bases in Call
  int* tpre;                                 // 33-entry tile prefix table
  float* la; float* lb; int* valid; float* acc;
  float* Xp; float* Yp; float* xn; float* yn;
  float* Fab; float* Faa; float* Gab; float* Gbb;   // ping-pong 2*PN / 2*PM
  int4* meta;   // per-row {coff, hoff, rs, bitcast(hb2)}
  float* fin;   // per-row final scale (0 if invalid)
  int* dsti;    // per-row destination index in padded potential array
  float* Call;
};

__device__ __forceinline__ float wredmax(float v){
  #pragma unroll
  for(int m=32;m>=1;m>>=1) v = fmaxf(v, __shfl_xor(v,m,64));
  return v;
}
__device__ __forceinline__ float wredsum(float v){
  #pragma unroll
  for(int m=32;m>=1;m>>=1) v += __shfl_xor(v,m,64);
  return v;
}

// ---------------- k_prep: single block does init+predict+offsets+pack+meta ----------------
__global__ void __launch_bounds__(1024) k_prep(Params p){
  __shared__ float cent[KC*DD];
  __shared__ int   spred[NN];
  __shared__ int   scx[KC], scy[KC], sfx[KC], sfy[KC];
  __shared__ int   sox[KC+1], soy[KC+1], spx[KC], spy[KC];
  __shared__ int   sbxy[KC], sbyx[KC], sbxx[KC], sbyy[KC], sval[KC];
  __shared__ float sla[KC], slb[KC];
  const int tid = threadIdx.x, nth = blockDim.x;

  // zero potentials (incl. pads) + done counter
  for(int i=tid;i<2*PN;i+=nth){ p.Fab[i]=0.f; p.Faa[i]=0.f; }
  for(int j=tid;j<2*PM;j+=nth){ p.Gab[j]=0.f; p.Gbb[j]=0.f; }
  if(tid==0) p.zr[0]=0;
  if(tid<KC){ scx[tid]=0; scy[tid]=0; sfx[tid]=0; sfy[tid]=0; }
  for(int i=tid;i<KC*DD;i+=nth) cent[i]=p.centers[i];
  __syncthreads();

  // predict + counts
  for(int i=tid;i<NN;i+=nth){
    const float4* xi = (const float4*)(p.x + i*DD);
    float best = 3.4e38f; int bk = 0;
    for(int k=0;k<KC;k++){
      const float4* ck = (const float4*)&cent[k*DD];
      float s = 0.f;
      #pragma unroll
      for(int q=0;q<DD/4;q++){ float4 a=xi[q], b=ck[q];
        float dx=a.x-b.x, dy=a.y-b.y, dz=a.z-b.z, dw=a.w-b.w;
        s += dx*dx+dy*dy+dz*dz+dw*dw; }
      if(s < best){ best = s; bk = k; }
    }
    spred[i]=bk;
    atomicAdd(&scx[bk],1);
  }
  for(int j=tid;j<MM;j+=nth) atomicAdd(&scy[p.predy[j]],1);
  __syncthreads();

  // serial phase (LDS-only latencies)
  if(tid==0){
    int ox=0, oy=0, px=0, py=0; float lf=0.f;
    for(int k=0;k<KC;k++){
      int nk=scx[k], mk=scy[k];
      sox[k]=ox; soy[k]=oy; spx[k]=px; spy[k]=py;
      ox+=nk; oy+=mk; px=(px+nk+3)&~3; py=(py+mk+3)&~3;
      sla[k] = -logf(fmaxf((float)nk,1.f));
      slb[k] = -logf(fmaxf((float)mk,1.f));
      sval[k] = (nk>0 && mk>0)?1:0;
      float df = (float)nk/(float)NN - p.ftarg[k];
      lf += df*df;
    }
    sox[KC]=ox; soy[KC]=oy;
    int run=0;
    for(int k=0;k<KC;k++){ int nk=scx[k], mk=scy[k]; sbxy[k]=run; run+=nk*((mk+3)&~3); }
    for(int k=0;k<KC;k++){ int nk=scx[k], mk=scy[k]; sbyx[k]=run; run+=mk*((nk+3)&~3); }
    for(int k=0;k<KC;k++){ int nk=scx[k];            sbxx[k]=run; run+=nk*((nk+3)&~3); }
    for(int k=0;k<KC;k++){ int mk=scy[k];            sbyy[k]=run; run+=mk*((mk+3)&~3); }
    // globals for k4 / k_iter
    for(int k=0;k<KC;k++){
      p.cntx[k]=scx[k]; p.cnty[k]=scy[k];
      p.off_x[k]=sox[k]; p.off_y[k]=soy[k];
      p.pox[k]=spx[k]; p.poy[k]=spy[k];
      p.bxy[k]=sbxy[k]; p.byx[k]=sbyx[k]; p.bxx[k]=sbxx[k]; p.byy[k]=sbyy[k];
      p.la[k]=sla[k]; p.lb[k]=slb[k]; p.valid[k]=sval[k];
    }
    // tile prefix for k4: order seg-major (XY,YX,XX,YY) x cluster
    int trun=0;
    for(int e=0;e<32;e++){
      int seg=e>>3, k=e&7;
      int nk=scx[k], mk=scy[k];
      int nrows = (seg==0)?nk:(seg==1)?mk:(seg==2)?nk:mk;
      int rs    = (seg==0)?((mk+3)&~3):(seg==1)?((nk+3)&~3):(seg==2)?((nk+3)&~3):((mk+3)&~3);
      p.tpre[e]=trun;
      trun += ((nrows+63)>>6) * ((rs+63)>>6);
    }
    p.tpre[32]=trun;
    *p.acc = lf/(float)KC;
  }
  __syncthreads();

  // pack
  for(int i=tid;i<NN;i+=nth){
    int k=spred[i];
    int pos = sox[k] + atomicAdd(&sfx[k],1);
    const float4* xi=(const float4*)(p.x+i*DD);
    float4* dst=(float4*)(p.Xp+(size_t)pos*DD);
    float s=0.f;
    #pragma unroll
    for(int q=0;q<DD/4;q++){ float4 v=xi[q]; dst[q]=v;
      s += v.x*v.x+v.y*v.y+v.z*v.z+v.w*v.w; }
    p.xn[pos]=s;
  }
  for(int j=tid;j<MM;j+=nth){
    int k=p.predy[j];
    int pos = soy[k] + atomicAdd(&sfy[k],1);
    const float4* yj=(const float4*)(p.y+j*DD);
    float4* dst=(float4*)(p.Yp+(size_t)pos*DD);
    float s=0.f;
    #pragma unroll
    for(int q=0;q<DD/4;q++){ float4 v=yj[q]; dst[q]=v;
      s += v.x*v.x+v.y*v.y+v.z*v.z+v.w*v.w; }
    p.yn[pos]=s;
  }

  // per-row metadata (cluster found by offset scan; no pc array needed)
  for(int row=tid; row<TOTROWS; row+=nth){
    int grp = (row>=NN) + (row>=NN+MM) + (row>=2*NN+MM);
    int pidx = row - ((grp==0)?0:(grp==1)?NN:(grp==2)?(NN+MM):(2*NN+MM));
    const int* offs = (grp==0||grp==2)? sox : soy;
    int k=0;
    #pragma unroll
    for(int q=1;q<KC;q++) if(pidx>=offs[q]) k=q;
    int r = pidx - offs[k];
    int nk=scx[k], mk=scy[k];
    int rsx=(nk+3)&~3, rsy=(mk+3)&~3;
    int coff, hoff, rs, di; float hc, fv;
    if(grp==0){ rs=rsy; coff=sbxy[k]+r*rs; hoff=spy[k]; hc=slb[k]; di=spx[k]+r;
      fv = sval[k] ?  1.f/(float)nk : 0.f; }
    else if(grp==1){ rs=rsx; coff=sbyx[k]+r*rs; hoff=spx[k]; hc=sla[k]; di=spy[k]+r;
      fv = sval[k] ?  1.f/(float)mk : 0.f; }
    else if(grp==2){ rs=rsx; coff=sbxx[k]+r*rs; hoff=spx[k]; hc=sla[k]; di=spx[k]+r;
      fv = sval[k] ? -1.f/(float)nk : 0.f; }
    else { rs=rsy; coff=sbyy[k]+r*rs; hoff=spy[k]; hc=slb[k]; di=spy[k]+r;
      fv = sval[k] ? -1.f/(float)mk : 0.f; }
    p.meta[row] = make_int4(coff, hoff, rs, __float_as_int(hc*INVLN2F));
    p.fin[row]  = fv;
    p.dsti[row] = di;
  }
}

// ---------------- k4: LDS-tiled cost build (64x64 tiles, B transposed) ----------------
__global__ void __launch_bounds__(256) k4_cost(Params p){
  __shared__ float As[64*68];
  __shared__ float Bt[64*68];
  const int tid = threadIdx.x;
  const int T = p.tpre[32];

  for(int tile=blockIdx.x; tile<T; tile+=gridDim.x){
    int e=0;
    for(int q=1;q<32;q++) if(tile>=p.tpre[q]) e=q;
    int seg=e>>3, k=e&7;
    int nk=p.cntx[k], mk=p.cnty[k];
    int rsx=(nk+3)&~3, rsy=(mk+3)&~3;
    const float *Apts, *Bpts, *nA, *nB; int nrows, ncol, rs, base;
    if(seg==0){ Apts=p.Xp+(size_t)p.off_x[k]*DD; Bpts=p.Yp+(size_t)p.off_y[k]*DD;
      nA=p.xn+p.off_x[k]; nB=p.yn+p.off_y[k]; nrows=nk; ncol=mk; rs=rsy; base=p.bxy[k]; }
    else if(seg==1){ Apts=p.Yp+(size_t)p.off_y[k]*DD; Bpts=p.Xp+(size_t)p.off_x[k]*DD;
      nA=p.yn+p.off_y[k]; nB=p.xn+p.off_x[k]; nrows=mk; ncol=nk; rs=rsx; base=p.byx[k]; }
    else if(seg==2){ Apts=p.Xp+(size_t)p.off_x[k]*DD; Bpts=Apts;
      nA=p.xn+p.off_x[k]; nB=nA; nrows=nk; ncol=nk; rs=rsx; base=p.bxx[k]; }
    else { Apts=p.Yp+(size_t)p.off_y[k]*DD; Bpts=Apts;
      nA=p.yn+p.off_y[k]; nB=nA; nrows=mk; ncol=mk; rs=rsy; base=p.byy[k]; }
    int ntc=(rs+63)>>6;
    int lt = tile - p.tpre[e];
    int tr = lt/ntc, tc = lt - tr*ntc;

    __syncthreads();
    for(int l=tid;l<1024;l+=256){
      int row=l>>4, c4=l&15;
      int gA=tr*64+row;
      float4 va = (gA<nrows)? ((const float4*)Apts)[gA*16+c4] : make_float4(0.f,0.f,0.f,0.f);
      *(float4*)&As[row*68 + c4*4] = va;
      int gB=tc*64+row;
      float4 vb = (gB<ncol)? ((const float4*)Bpts)[gB*16+c4] : make_float4(0.f,0.f,0.f,0.f);
      Bt[(c4*4+0)*68+row]=vb.x; Bt[(c4*4+1)*68+row]=vb.y;
      Bt[(c4*4+2)*68+row]=vb.z; Bt[(c4*4+3)*68+row]=vb.w;
    }
    __syncthreads();

    int tx=tid&15, ty=tid>>4;
    float4 acc[4] = {make_float4(0,0,0,0),make_float4(0,0,0,0),
                     make_float4(0,0,0,0),make_float4(0,0,0,0)};
    for(int kk=0;kk<64;kk+=4){
      float4 a0=*(float4*)&As[(ty*4+0)*68+kk];
      float4 a1=*(float4*)&As[(ty*4+1)*68+kk];
      float4 a2=*(float4*)&As[(ty*4+2)*68+kk];
      float4 a3=*(float4*)&As[(ty*4+3)*68+kk];
      float4 b0=*(float4*)&Bt[(kk+0)*68+tx*4];
      float4 b1=*(float4*)&Bt[(kk+1)*68+tx*4];
      float4 b2=*(float4*)&Bt[(kk+2)*68+tx*4];
      float4 b3=*(float4*)&Bt[(kk+3)*68+tx*4];
      #define ACCROW(i,AI) \
        acc[i].x = fmaf(AI.x,b0.x, fmaf(AI.y,b1.x, fmaf(AI.z,b2.x, fmaf(AI.w,b3.x, acc[i].x)))); \
        acc[i].y = fmaf(AI.x,b0.y, fmaf(AI.y,b1.y, fmaf(AI.z,b2.y, fmaf(AI.w,b3.y, acc[i].y)))); \
        acc[i].z = fmaf(AI.x,b0.z, fmaf(AI.y,b1.z, fmaf(AI.z,b2.z, fmaf(AI.w,b3.z, acc[i].z)))); \
        acc[i].w = fmaf(AI.x,b0.w, fmaf(AI.y,b1.w, fmaf(AI.z,b2.w, fmaf(AI.w,b3.w, acc[i].w))));
      ACCROW(0,a0) ACCROW(1,a1) ACCROW(2,a2) ACCROW(3,a3)
      #undef ACCROW
    }

    int gc0 = tc*64 + tx*4;
    #pragma unroll
    for(int i=0;i<4;i++){
      int gr = tr*64 + ty*4 + i;
      if(gr >= nrows) continue;
      float xr = nA[gr];
      float v[4]; float d[4]={acc[i].x,acc[i].y,acc[i].z,acc[i].w};
      #pragma unroll
      for(int j=0;j<4;j++){
        int gc = gc0+j;
        v[j] = PADV;
        if(gc < ncol) v[j] = 0.5f*fmaxf(xr + nB[gc] - 2.f*d[j], 0.f);
      }
      if(gc0+3 < rs){
        *(float4*)&p.Call[(size_t)base + (size_t)gr*rs + gc0] = make_float4(v[0],v[1],v[2],v[3]);
      } else {
        for(int j=0;j<4;j++) if(gc0+j < rs) p.Call[(size_t)base + (size_t)gr*rs + gc0+j] = v[j];
      }
    }
  }
}

// ---------------- k_iter: one Jacobi eps-step, 2 rows per wave ----------------
__global__ void __launch_bounds__(256) k_iter(Params p, float eps, int cur){
  const int w = blockIdx.x*4 + (threadIdx.x>>6);
  const int lane = threadIdx.x & 63;
  const int r0 = w*2, r1 = r0+1;
  const int grp = (r0>=NN) + (r0>=NN+MM) + (r0>=2*NN+MM);   // pairs never straddle
  const float* po; float* fam; int famN;
  if(grp==0){ po=p.Gab+cur*PM; fam=p.Fab; famN=PN; }
  else if(grp==1){ po=p.Fab+cur*PN; fam=p.Gab; famN=PM; }
  else if(grp==2){ po=p.Faa+cur*PN; fam=p.Faa; famN=PN; }
  else { po=p.Gbb+cur*PM; fam=p.Gbb; famN=PM; }

  int4 m0 = p.meta[r0], m1 = p.meta[r1];
  const float* C0=p.Call+m0.x; const float* P0=po+m0.y; float h0=__int_as_float(m0.w);
  const float* C1=p.Call+m1.x; const float* P1=po+m1.y; float h1=__int_as_float(m1.w);
  const int rs0=m0.z, rs1=m1.z, rsm = rs0>rs1?rs0:rs1;
  const float s1 = (1.0f/eps)*INVLN2F;

  float mA=-3.4e38f,sA=0.f,mB=-3.4e38f,sB=0.f;
  for(int c0=lane*4; c0<rsm; c0+=256){
    if(c0<rs0){
      float4 cv=*(const float4*)(C0+c0), pv=*(const float4*)(P0+c0);
      float w0=fmaf(pv.x-cv.x,s1,h0), w1=fmaf(pv.y-cv.y,s1,h0);
      float w2=fmaf(pv.z-cv.z,s1,h0), w3=fmaf(pv.w-cv.w,s1,h0);
      float lm=fmaxf(fmaxf(w0,w1),fmaxf(w2,w3));
      float mn=fmaxf(mA,lm);
      sA = sA*exp2f(mA-mn) + (exp2f(w0-mn)+exp2f(w1-mn)) + (exp2f(w2-mn)+exp2f(w3-mn));
      mA = mn;
    }
    if(c0<rs1){
      float4 cv=*(const float4*)(C1+c0), pv=*(const float4*)(P1+c0);
      float w0=fmaf(pv.x-cv.x,s1,h1), w1=fmaf(pv.y-cv.y,s1,h1);
      float w2=fmaf(pv.z-cv.z,s1,h1), w3=fmaf(pv.w-cv.w,s1,h1);
      float lm=fmaxf(fmaxf(w0,w1),fmaxf(w2,w3));
      float mn=fmaxf(mB,lm);
      sB = sB*exp2f(mB-mn) + (exp2f(w0-mn)+exp2f(w1-mn)) + (exp2f(w2-mn)+exp2f(w3-mn));
      mB = mn;
    }
  }
  float MA=wredmax(mA); float SA=wredsum(sA*exp2f(mA-MA));
  float MB=wredmax(mB); float SB=wredsum(sB*exp2f(mB-MB));
  float LA = -eps*LN2F*(MA + log2f(SA));
  float LB = -eps*LN2F*(MB + log2f(SB));

  if(lane==0){
    int d0=p.dsti[r0], d1=p.dsti[r1];
    fam[(1-cur)*famN+d0] = 0.5f*(fam[cur*famN+d0]+LA);
    fam[(1-cur)*famN+d1] = 0.5f*(fam[cur*famN+d1]+LB);
  }
}

// ---------------- k_final: extrapolation at eps_min + reduction + out-write ----------------
__global__ void __launch_bounds__(256) k_final(Params p, float eps, int cur){
  __shared__ float bacc;
  if(threadIdx.x==0) bacc=0.f;
  __syncthreads();
  const int w = blockIdx.x*4 + (threadIdx.x>>6);
  const int lane = threadIdx.x & 63;
  const float s1 = (1.0f/eps)*INVLN2F;

  #pragma unroll
  for(int hh=0; hh<2; ++hh){
    int row = w*2 + hh;
    float fv = p.fin[row];
    if(fv == 0.f) continue;
    int grp = (row>=NN) + (row>=NN+MM) + (row>=2*NN+MM);
    const float* po = (grp==0)?(p.Gab+cur*PM):(grp==1)?(p.Fab+cur*PN)
                     :(grp==2)?(p.Faa+cur*PN):(p.Gbb+cur*PM);
    int4 mt = p.meta[row];
    const float* Cb=p.Call+mt.x; const float* Pv=po+mt.y; float hb=__int_as_float(mt.w);
    float m=-3.4e38f, s=0.f;
    for(int c0=lane*4; c0<mt.z; c0+=256){
      float4 cv=*(const float4*)(Cb+c0), pv=*(const float4*)(Pv+c0);
      float w0=fmaf(pv.x-cv.x,s1,hb), w1=fmaf(pv.y-cv.y,s1,hb);
      float w2=fmaf(pv.z-cv.z,s1,hb), w3=fmaf(pv.w-cv.w,s1,hb);
      float lm=fmaxf(fmaxf(w0,w1),fmaxf(w2,w3));
      float mn=fmaxf(m,lm);
      s = s*exp2f(m-mn) + (exp2f(w0-mn)+exp2f(w1-mn)) + (exp2f(w2-mn)+exp2f(w3-mn));
      m = mn;
    }
    float M=wredmax(m); float S=wredsum(s*exp2f(m-M));
    float L = -eps*LN2F*(M + log2f(S));
    if(lane==0) atomicAdd(&bacc, L*fv);
  }
  __syncthreads();
  if(threadIdx.x==0){
    if(bacc != 0.f) atomicAdd(p.acc, bacc);
    __threadfence();
    int prev = __hip_atomic_fetch_add(p.zr, 1, __ATOMIC_ACQ_REL, __HIP_MEMORY_SCOPE_AGENT);
    if(prev == (int)gridDim.x-1){
      __threadfence();
      p.out[0] = __hip_atomic_load(p.acc, __ATOMIC_RELAXED, __HIP_MEMORY_SCOPE_AGENT);
    }
  }
}

extern "C" void kernel_launch(void* const* d_in, const int* in_sizes, int n_in,
                              void* d_out, int out_size, void* d_ws, size_t ws_size,
                              hipStream_t stream)
{
  Params p;
  p.x       = (const float*)d_in[0];
  p.centers = (const float*)d_in[1];
  p.ftarg   = (const float*)d_in[2];
  p.y       = (const float*)d_in[3];
  p.predy   = (const int*)d_in[4];
  p.out     = (float*)d_out;

  char* w = (char*)d_ws; size_t o = 0;
  auto A = [&](size_t bytes)->char*{ char* r = w + o; o = (o + bytes + 255) & ~(size_t)255; return r; };
  p.zr   =(int*)A(64*4);
  p.cntx =(int*)A(KC*4); p.cnty=(int*)A(KC*4);
  p.off_x=(int*)A(KC*4); p.off_y=(int*)A(KC*4);
  p.pox  =(int*)A(KC*4); p.poy =(int*)A(KC*4);
  p.bxy  =(int*)A(KC*4); p.byx =(int*)A(KC*4);
  p.bxx  =(int*)A(KC*4); p.byy =(int*)A(KC*4);
  p.tpre =(int*)A(33*4);
  p.la=(float*)A(KC*4); p.lb=(float*)A(KC*4); p.valid=(int*)A(KC*4);
  p.acc=(float*)A(4);
  p.Xp=(float*)A((size_t)NN*DD*4); p.Yp=(float*)A((size_t)MM*DD*4);
  p.xn=(float*)A(NN*4); p.yn=(float*)A(MM*4);
  p.Fab=(float*)A((size_t)2*PN*4); p.Faa=(float*)A((size_t)2*PN*4);
  p.Gab=(float*)A((size_t)2*PM*4); p.Gbb=(float*)A((size_t)2*PM*4);
  p.meta=(int4*)A((size_t)TOTROWS*16);
  p.fin =(float*)A((size_t)TOTROWS*4);
  p.dsti=(int*)A((size_t)TOTROWS*4);
  p.Call=(float*)A((size_t)CPAD*4);

  hipLaunchKernelGGL(k_prep,  dim3(1),    dim3(1024), 0, stream, p);
  hipLaunchKernelGGL(k4_cost, dim3(1024), dim3(256),  0, stream, p);

  const double EMIN = 0.05*0.05, S2 = 0.8*0.8;
  float epsv[40]; int ne = 0;
  { double e = 16.0; while(e > EMIN){ epsv[ne++] = (float)e; e *= S2; } epsv[ne++] = (float)EMIN; }

  for(int it=0; it<ne; ++it)
    hipLaunchKernelGGL(k_iter, dim3(TOTROWS/8), dim3(256), 0, stream, p, epsv[it], it&1);

  hipLaunchKernelGGL(k_final, dim3(TOTROWS/8), dim3(256), 0, stream, p, (float)EMIN, ne&1);
}

// Round 7
// 309.901 us; speedup vs baseline: 7.8405x; 1.1898x over previous
//
#include <hip/hip_runtime.h>

#define NN 2048
#define MM 2048
#define KC 8
#define DD 64
#define PN (NN + 4*KC + 32)
#define PM (MM + 4*KC + 32)
#define TOTROWS (2*(NN+MM))
#define CPAD (2*NN*MM + NN*NN + MM*MM + 6*(NN+MM) + 256)
#define PADV 3.0e38f
#define LN2F    0.6931471805599453f
#define INVLN2F 1.4426950408889634f

// zr layout (ints): [0]=done counter, [8..15]=cnt_x, [16..23]=cnt_y,
//                   [24..31]=fill_x, [32..39]=fill_y
struct Params {
  const float* x; const float* centers; const float* ftarg;
  const float* y; const int* predy;
  float* out;
  int* zr;
  int* pred_x;
  int* cntx; int* cnty; int* off_x; int* off_y; int* pox; int* poy;
  int* bxy; int* byx; int* bxx; int* byy;    // per-cluster segment bases in Call
  int* tpre;                                 // 33-entry tile prefix table
  float* la; float* lb; int* valid; float* acc;
  float* Xp; float* Yp; float* xn; float* yn;
  float* Fab; float* Faa; float* Gab; float* Gbb;   // ping-pong 2*PN / 2*PM
  int4* meta;   // per-row {coff, hoff, rs, bitcast(hb2)}
  float* fin;   // per-row final scale (0 if invalid)
  int* dsti;    // per-row destination index in padded potential array
  float* Call;
};

__device__ __forceinline__ float wredmax(float v){
  #pragma unroll
  for(int m=32;m>=1;m>>=1) v = fmaxf(v, __shfl_xor(v,m,64));
  return v;
}
__device__ __forceinline__ float wredsum(float v){
  #pragma unroll
  for(int m=32;m>=1;m>>=1) v += __shfl_xor(v,m,64);
  return v;
}

// ---------------- k_pred: zero potentials + kmeans predict + counts (parallel) ----------------
__global__ void __launch_bounds__(256) k_pred(Params p){
  const int gtid = blockIdx.x*blockDim.x + threadIdx.x;
  const int nth  = gridDim.x*blockDim.x;

  for(int i=gtid;i<2*PN;i+=nth){ p.Fab[i]=0.f; p.Faa[i]=0.f; }
  for(int j=gtid;j<2*PM;j+=nth){ p.Gab[j]=0.f; p.Gbb[j]=0.f; }

  for(int i=gtid;i<NN;i+=nth){
    const float4* xi = (const float4*)(p.x + i*DD);
    float best = 3.4e38f; int bk = 0;
    for(int k=0;k<KC;k++){
      const float4* ck = (const float4*)(p.centers + k*DD);
      float s = 0.f;
      #pragma unroll
      for(int q=0;q<DD/4;q++){ float4 a=xi[q], b=ck[q];
        float dx=a.x-b.x, dy=a.y-b.y, dz=a.z-b.z, dw=a.w-b.w;
        s += dx*dx+dy*dy+dz*dz+dw*dw; }
      if(s < best){ best = s; bk = k; }
    }
    p.pred_x[i] = bk;
    atomicAdd(&p.zr[8+bk], 1);
  }
  for(int j=gtid;j<MM;j+=nth) atomicAdd(&p.zr[16 + p.predy[j]], 1);
}

// ---------------- k_pack: per-block redundant serial phase + pack + row meta ----------------
__global__ void __launch_bounds__(256) k_pack(Params p){
  __shared__ int scx[KC], scy[KC];
  __shared__ int sox[KC+1], soy[KC+1], spx[KC], spy[KC];
  __shared__ int sbxy[KC], sbyx[KC], sbxx[KC], sbyy[KC], sval[KC];
  __shared__ float sla[KC], slb[KC];
  const int tid = threadIdx.x;
  const int gtid = blockIdx.x*blockDim.x + tid;
  const int nth  = gridDim.x*blockDim.x;

  if(tid==0){
    int ox=0, oy=0, px=0, py=0; float lf=0.f;
    for(int k=0;k<KC;k++){
      int nk=p.zr[8+k], mk=p.zr[16+k];
      scx[k]=nk; scy[k]=mk;
      sox[k]=ox; soy[k]=oy; spx[k]=px; spy[k]=py;
      ox+=nk; oy+=mk; px=(px+nk+3)&~3; py=(py+mk+3)&~3;
      sla[k] = -logf(fmaxf((float)nk,1.f));
      slb[k] = -logf(fmaxf((float)mk,1.f));
      sval[k] = (nk>0 && mk>0)?1:0;
      float df = (float)nk/(float)NN - p.ftarg[k];
      lf += df*df;
    }
    sox[KC]=ox; soy[KC]=oy;
    int run=0;
    for(int k=0;k<KC;k++){ int nk=scx[k], mk=scy[k]; sbxy[k]=run; run+=nk*((mk+3)&~3); }
    for(int k=0;k<KC;k++){ int nk=scx[k], mk=scy[k]; sbyx[k]=run; run+=mk*((nk+3)&~3); }
    for(int k=0;k<KC;k++){ int nk=scx[k];            sbxx[k]=run; run+=nk*((nk+3)&~3); }
    for(int k=0;k<KC;k++){ int mk=scy[k];            sbyy[k]=run; run+=mk*((mk+3)&~3); }
    if(blockIdx.x==0){
      for(int k=0;k<KC;k++){
        p.cntx[k]=scx[k]; p.cnty[k]=scy[k];
        p.off_x[k]=sox[k]; p.off_y[k]=soy[k];
        p.pox[k]=spx[k]; p.poy[k]=spy[k];
        p.bxy[k]=sbxy[k]; p.byx[k]=sbyx[k]; p.bxx[k]=sbxx[k]; p.byy[k]=sbyy[k];
        p.la[k]=sla[k]; p.lb[k]=slb[k]; p.valid[k]=sval[k];
      }
      int trun=0;
      for(int e=0;e<32;e++){
        int seg=e>>3, k=e&7;
        int nk=scx[k], mk=scy[k];
        int nrows = (seg==0)?nk:(seg==1)?mk:(seg==2)?nk:mk;
        int rs    = (seg==0)?((mk+3)&~3):(seg==1)?((nk+3)&~3):(seg==2)?((nk+3)&~3):((mk+3)&~3);
        p.tpre[e]=trun;
        trun += ((nrows+63)>>6) * ((rs+63)>>6);
      }
      p.tpre[32]=trun;
      *p.acc = lf/(float)KC;
    }
  }
  __syncthreads();

  // pack (positions via global fill counters)
  for(int i=gtid;i<NN;i+=nth){
    int k=p.pred_x[i];
    int pos = sox[k] + atomicAdd(&p.zr[24+k],1);
    const float4* xi=(const float4*)(p.x+i*DD);
    float4* dst=(float4*)(p.Xp+(size_t)pos*DD);
    float s=0.f;
    #pragma unroll
    for(int q=0;q<DD/4;q++){ float4 v=xi[q]; dst[q]=v;
      s += v.x*v.x+v.y*v.y+v.z*v.z+v.w*v.w; }
    p.xn[pos]=s;
  }
  for(int j=gtid;j<MM;j+=nth){
    int k=p.predy[j];
    int pos = soy[k] + atomicAdd(&p.zr[32+k],1);
    const float4* yj=(const float4*)(p.y+j*DD);
    float4* dst=(float4*)(p.Yp+(size_t)pos*DD);
    float s=0.f;
    #pragma unroll
    for(int q=0;q<DD/4;q++){ float4 v=yj[q]; dst[q]=v;
      s += v.x*v.x+v.y*v.y+v.z*v.z+v.w*v.w; }
    p.yn[pos]=s;
  }

  // per-row metadata
  for(int row=gtid; row<TOTROWS; row+=nth){
    int grp = (row>=NN) + (row>=NN+MM) + (row>=2*NN+MM);
    int pidx = row - ((grp==0)?0:(grp==1)?NN:(grp==2)?(NN+MM):(2*NN+MM));
    const int* offs = (grp==0||grp==2)? sox : soy;
    int k=0;
    #pragma unroll
    for(int q=1;q<KC;q++) if(pidx>=offs[q]) k=q;
    int r = pidx - offs[k];
    int nk=scx[k], mk=scy[k];
    int rsx=(nk+3)&~3, rsy=(mk+3)&~3;
    int coff, rs, di; float hc, fv; int hoff;
    if(grp==0){ rs=rsy; coff=sbxy[k]+r*rs; hoff=spy[k]; hc=slb[k]; di=spx[k]+r;
      fv = sval[k] ?  1.f/(float)nk : 0.f; }
    else if(grp==1){ rs=rsx; coff=sbyx[k]+r*rs; hoff=spx[k]; hc=sla[k]; di=spy[k]+r;
      fv = sval[k] ?  1.f/(float)mk : 0.f; }
    else if(grp==2){ rs=rsx; coff=sbxx[k]+r*rs; hoff=spx[k]; hc=sla[k]; di=spx[k]+r;
      fv = sval[k] ? -1.f/(float)nk : 0.f; }
    else { rs=rsy; coff=sbyy[k]+r*rs; hoff=spy[k]; hc=slb[k]; di=spy[k]+r;
      fv = sval[k] ? -1.f/(float)mk : 0.f; }
    p.meta[row] = make_int4(coff, hoff, rs, __float_as_int(hc*INVLN2F));
    p.fin[row]  = fv;
    p.dsti[row] = di;
  }
}

// ---------------- k4: LDS-tiled cost build (64x64 tiles, B transposed) ----------------
__global__ void __launch_bounds__(256) k4_cost(Params p){
  __shared__ float As[64*68];
  __shared__ float Bt[64*68];
  const int tid = threadIdx.x;
  const int T = p.tpre[32];

  for(int tile=blockIdx.x; tile<T; tile+=gridDim.x){
    int e=0;
    for(int q=1;q<32;q++) if(tile>=p.tpre[q]) e=q;
    int seg=e>>3, k=e&7;
    int nk=p.cntx[k], mk=p.cnty[k];
    int rsx=(nk+3)&~3, rsy=(mk+3)&~3;
    const float *Apts, *Bpts, *nA, *nB; int nrows, ncol, rs, base;
    if(seg==0){ Apts=p.Xp+(size_t)p.off_x[k]*DD; Bpts=p.Yp+(size_t)p.off_y[k]*DD;
      nA=p.xn+p.off_x[k]; nB=p.yn+p.off_y[k]; nrows=nk; ncol=mk; rs=rsy; base=p.bxy[k]; }
    else if(seg==1){ Apts=p.Yp+(size_t)p.off_y[k]*DD; Bpts=p.Xp+(size_t)p.off_x[k]*DD;
      nA=p.yn+p.off_y[k]; nB=p.xn+p.off_x[k]; nrows=mk; ncol=nk; rs=rsx; base=p.byx[k]; }
    else if(seg==2){ Apts=p.Xp+(size_t)p.off_x[k]*DD; Bpts=Apts;
      nA=p.xn+p.off_x[k]; nB=nA; nrows=nk; ncol=nk; rs=rsx; base=p.bxx[k]; }
    else { Apts=p.Yp+(size_t)p.off_y[k]*DD; Bpts=Apts;
      nA=p.yn+p.off_y[k]; nB=nA; nrows=mk; ncol=mk; rs=rsy; base=p.byy[k]; }
    int ntc=(rs+63)>>6;
    int lt = tile - p.tpre[e];
    int tr = lt/ntc, tc = lt - tr*ntc;

    __syncthreads();
    for(int l=tid;l<1024;l+=256){
      int row=l>>4, c4=l&15;
      int gA=tr*64+row;
      float4 va = (gA<nrows)? ((const float4*)Apts)[gA*16+c4] : make_float4(0.f,0.f,0.f,0.f);
      *(float4*)&As[row*68 + c4*4] = va;
      int gB=tc*64+row;
      float4 vb = (gB<ncol)? ((const float4*)Bpts)[gB*16+c4] : make_float4(0.f,0.f,0.f,0.f);
      Bt[(c4*4+0)*68+row]=vb.x; Bt[(c4*4+1)*68+row]=vb.y;
      Bt[(c4*4+2)*68+row]=vb.z; Bt[(c4*4+3)*68+row]=vb.w;
    }
    __syncthreads();

    int tx=tid&15, ty=tid>>4;
    float4 acc[4] = {make_float4(0,0,0,0),make_float4(0,0,0,0),
                     make_float4(0,0,0,0),make_float4(0,0,0,0)};
    for(int kk=0;kk<64;kk+=4){
      float4 a0=*(float4*)&As[(ty*4+0)*68+kk];
      float4 a1=*(float4*)&As[(ty*4+1)*68+kk];
      float4 a2=*(float4*)&As[(ty*4+2)*68+kk];
      float4 a3=*(float4*)&As[(ty*4+3)*68+kk];
      float4 b0=*(float4*)&Bt[(kk+0)*68+tx*4];
      float4 b1=*(float4*)&Bt[(kk+1)*68+tx*4];
      float4 b2=*(float4*)&Bt[(kk+2)*68+tx*4];
      float4 b3=*(float4*)&Bt[(kk+3)*68+tx*4];
      #define ACCROW(i,AI) \
        acc[i].x = fmaf(AI.x,b0.x, fmaf(AI.y,b1.x, fmaf(AI.z,b2.x, fmaf(AI.w,b3.x, acc[i].x)))); \
        acc[i].y = fmaf(AI.x,b0.y, fmaf(AI.y,b1.y, fmaf(AI.z,b2.y, fmaf(AI.w,b3.y, acc[i].y)))); \
        acc[i].z = fmaf(AI.x,b0.z, fmaf(AI.y,b1.z, fmaf(AI.z,b2.z, fmaf(AI.w,b3.z, acc[i].z)))); \
        acc[i].w = fmaf(AI.x,b0.w, fmaf(AI.y,b1.w, fmaf(AI.w,b3.w, fmaf(AI.z,b2.w, acc[i].w))));
      ACCROW(0,a0) ACCROW(1,a1) ACCROW(2,a2) ACCROW(3,a3)
      #undef ACCROW
    }

    int gc0 = tc*64 + tx*4;
    #pragma unroll
    for(int i=0;i<4;i++){
      int gr = tr*64 + ty*4 + i;
      if(gr >= nrows) continue;
      float xr = nA[gr];
      float v[4]; float d[4]={acc[i].x,acc[i].y,acc[i].z,acc[i].w};
      #pragma unroll
      for(int j=0;j<4;j++){
        int gc = gc0+j;
        v[j] = PADV;
        if(gc < ncol) v[j] = 0.5f*fmaxf(xr + nB[gc] - 2.f*d[j], 0.f);
      }
      if(gc0+3 < rs){
        *(float4*)&p.Call[(size_t)base + (size_t)gr*rs + gc0] = make_float4(v[0],v[1],v[2],v[3]);
      } else {
        for(int j=0;j<4;j++) if(gc0+j < rs) p.Call[(size_t)base + (size_t)gr*rs + gc0+j] = v[j];
      }
    }
  }
}

// ---------------- k_iter: one Jacobi eps-step, 2 rows per wave ----------------
__global__ void __launch_bounds__(256) k_iter(Params p, float eps, int cur){
  const int w = blockIdx.x*4 + (threadIdx.x>>6);
  const int lane = threadIdx.x & 63;
  const int r0 = w*2, r1 = r0+1;
  const int grp = (r0>=NN) + (r0>=NN+MM) + (r0>=2*NN+MM);   // pairs never straddle
  const float* po; float* fam; int famN;
  if(grp==0){ po=p.Gab+cur*PM; fam=p.Fab; famN=PN; }
  else if(grp==1){ po=p.Fab+cur*PN; fam=p.Gab; famN=PM; }
  else if(grp==2){ po=p.Faa+cur*PN; fam=p.Faa; famN=PN; }
  else { po=p.Gbb+cur*PM; fam=p.Gbb; famN=PM; }

  int4 m0 = p.meta[r0], m1 = p.meta[r1];
  const float* C0=p.Call+m0.x; const float* P0=po+m0.y; float h0=__int_as_float(m0.w);
  const float* C1=p.Call+m1.x; const float* P1=po+m1.y; float h1=__int_as_float(m1.w);
  const int rs0=m0.z, rs1=m1.z, rsm = rs0>rs1?rs0:rs1;
  const float s1 = (1.0f/eps)*INVLN2F;

  float mA=-3.4e38f,sA=0.f,mB=-3.4e38f,sB=0.f;
  for(int c0=lane*4; c0<rsm; c0+=256){
    if(c0<rs0){
      float4 cv=*(const float4*)(C0+c0), pv=*(const float4*)(P0+c0);
      float w0=fmaf(pv.x-cv.x,s1,h0), w1=fmaf(pv.y-cv.y,s1,h0);
      float w2=fmaf(pv.z-cv.z,s1,h0), w3=fmaf(pv.w-cv.w,s1,h0);
      float lm=fmaxf(fmaxf(w0,w1),fmaxf(w2,w3));
      float mn=fmaxf(mA,lm);
      sA = sA*exp2f(mA-mn) + (exp2f(w0-mn)+exp2f(w1-mn)) + (exp2f(w2-mn)+exp2f(w3-mn));
      mA = mn;
    }
    if(c0<rs1){
      float4 cv=*(const float4*)(C1+c0), pv=*(const float4*)(P1+c0);
      float w0=fmaf(pv.x-cv.x,s1,h1), w1=fmaf(pv.y-cv.y,s1,h1);
      float w2=fmaf(pv.z-cv.z,s1,h1), w3=fmaf(pv.w-cv.w,s1,h1);
      float lm=fmaxf(fmaxf(w0,w1),fmaxf(w2,w3));
      float mn=fmaxf(mB,lm);
      sB = sB*exp2f(mB-mn) + (exp2f(w0-mn)+exp2f(w1-mn)) + (exp2f(w2-mn)+exp2f(w3-mn));
      mB = mn;
    }
  }
  float MA=wredmax(mA); float SA=wredsum(sA*exp2f(mA-MA));
  float MB=wredmax(mB); float SB=wredsum(sB*exp2f(mB-MB));
  float LA = -eps*LN2F*(MA + log2f(SA));
  float LB = -eps*LN2F*(MB + log2f(SB));

  if(lane==0){
    int d0=p.dsti[r0], d1=p.dsti[r1];
    fam[(1-cur)*famN+d0] = 0.5f*(fam[cur*famN+d0]+LA);
    fam[(1-cur)*famN+d1] = 0.5f*(fam[cur*famN+d1]+LB);
  }
}

// ---------------- k_final: extrapolation at eps_min + reduction + out-write ----------------
__global__ void __launch_bounds__(256) k_final(Params p, float eps, int cur){
  __shared__ float bacc;
  if(threadIdx.x==0) bacc=0.f;
  __syncthreads();
  const int w = blockIdx.x*4 + (threadIdx.x>>6);
  const int lane = threadIdx.x & 63;
  const float s1 = (1.0f/eps)*INVLN2F;

  #pragma unroll
  for(int hh=0; hh<2; ++hh){
    int row = w*2 + hh;
    float fv = p.fin[row];
    if(fv == 0.f) continue;
    int grp = (row>=NN) + (row>=NN+MM) + (row>=2*NN+MM);
    const float* po = (grp==0)?(p.Gab+cur*PM):(grp==1)?(p.Fab+cur*PN)
                     :(grp==2)?(p.Faa+cur*PN):(p.Gbb+cur*PM);
    int4 mt = p.meta[row];
    const float* Cb=p.Call+mt.x; const float* Pv=po+mt.y; float hb=__int_as_float(mt.w);
    float m=-3.4e38f, s=0.f;
    for(int c0=lane*4; c0<mt.z; c0+=256){
      float4 cv=*(const float4*)(Cb+c0), pv=*(const float4*)(Pv+c0);
      float w0=fmaf(pv.x-cv.x,s1,hb), w1=fmaf(pv.y-cv.y,s1,hb);
      float w2=fmaf(pv.z-cv.z,s1,hb), w3=fmaf(pv.w-cv.w,s1,hb);
      float lm=fmaxf(fmaxf(w0,w1),fmaxf(w2,w3));
      float mn=fmaxf(m,lm);
      s = s*exp2f(m-mn) + (exp2f(w0-mn)+exp2f(w1-mn)) + (exp2f(w2-mn)+exp2f(w3-mn));
      m = mn;
    }
    float M=wredmax(m); float S=wredsum(s*exp2f(m-M));
    float L = -eps*LN2F*(M + log2f(S));
    if(lane==0) atomicAdd(&bacc, L*fv);
  }
  __syncthreads();
  if(threadIdx.x==0){
    if(bacc != 0.f) atomicAdd(p.acc, bacc);
    __threadfence();
    int prev = __hip_atomic_fetch_add(p.zr, 1, __ATOMIC_ACQ_REL, __HIP_MEMORY_SCOPE_AGENT);
    if(prev == (int)gridDim.x-1){
      __threadfence();
      p.out[0] = __hip_atomic_load(p.acc, __ATOMIC_RELAXED, __HIP_MEMORY_SCOPE_AGENT);
    }
  }
}

extern "C" void kernel_launch(void* const* d_in, const int* in_sizes, int n_in,
                              void* d_out, int out_size, void* d_ws, size_t ws_size,
                              hipStream_t stream)
{
  Params p;
  p.x       = (const float*)d_in[0];
  p.centers = (const float*)d_in[1];
  p.ftarg   = (const float*)d_in[2];
  p.y       = (const float*)d_in[3];
  p.predy   = (const int*)d_in[4];
  p.out     = (float*)d_out;

  char* w = (char*)d_ws; size_t o = 0;
  auto A = [&](size_t bytes)->char*{ char* r = w + o; o = (o + bytes + 255) & ~(size_t)255; return r; };
  p.zr   =(int*)A(64*4);
  p.pred_x=(int*)A(NN*4);
  p.cntx =(int*)A(KC*4); p.cnty=(int*)A(KC*4);
  p.off_x=(int*)A(KC*4); p.off_y=(int*)A(KC*4);
  p.pox  =(int*)A(KC*4); p.poy =(int*)A(KC*4);
  p.bxy  =(int*)A(KC*4); p.byx =(int*)A(KC*4);
  p.bxx  =(int*)A(KC*4); p.byy =(int*)A(KC*4);
  p.tpre =(int*)A(33*4);
  p.la=(float*)A(KC*4); p.lb=(float*)A(KC*4); p.valid=(int*)A(KC*4);
  p.acc=(float*)A(4);
  p.Xp=(float*)A((size_t)NN*DD*4); p.Yp=(float*)A((size_t)MM*DD*4);
  p.xn=(float*)A(NN*4); p.yn=(float*)A(MM*4);
  p.Fab=(float*)A((size_t)2*PN*4); p.Faa=(float*)A((size_t)2*PN*4);
  p.Gab=(float*)A((size_t)2*PM*4); p.Gbb=(float*)A((size_t)2*PM*4);
  p.meta=(int4*)A((size_t)TOTROWS*16);
  p.fin =(float*)A((size_t)TOTROWS*4);
  p.dsti=(int*)A((size_t)TOTROWS*4);
  p.Call=(float*)A((size_t)CPAD*4);

  hipMemsetAsync(p.zr, 0, 64*4, stream);
  hipLaunchKernelGGL(k_pred,  dim3(16),   dim3(256), 0, stream, p);
  hipLaunchKernelGGL(k_pack,  dim3(32),   dim3(256), 0, stream, p);
  hipLaunchKernelGGL(k4_cost, dim3(1024), dim3(256), 0, stream, p);

  const double EMIN = 0.05*0.05, S2 = 0.8*0.8;
  float epsv[40]; int ne = 0;
  { double e = 16.0; while(e > EMIN){ epsv[ne++] = (float)e; e *= S2; } epsv[ne++] = (float)EMIN; }

  for(int it=0; it<ne; ++it)
    hipLaunchKernelGGL(k_iter, dim3(TOTROWS/8), dim3(256), 0, stream, p, epsv[it], it&1);

  hipLaunchKernelGGL(k_final, dim3(TOTROWS/8), dim3(256), 0, stream, p, (float)EMIN, ne&1);
}